// Round 7
// baseline (104.870 us; speedup 1.0000x reference)
//
#include <hip/hip_runtime.h>
#include <math.h>

// FutureEncoder: B=4, S=2048, D=1024, FUTURE_K=32, fp32 in/out.
// R10 = R9 resubmission (round-6 bench was a broker/container infra failure,
// same as round 0; kernel audit found no hang/crash hazard).
//   Kernel A: scores via split-bf16 MFMA + LDS reduce + softmax -> weights
//             wm[8192][32] fp32 in workspace (poisoned anyway, so free).
//   Kernel B: PV as a pure streaming kernel: 8 tokens/block, 256 threads,
//             fully-static 39-row sliding window, weights staged in LDS.
// Numerics identical to R5-R8 (RNE split-bf16 3-product scores, fp32 PV).

constexpr int S_CONST = 2048;
constexpr int D = 1024;
constexpr int G = 16;            // tokens per scores-block
constexpr int NTOK = 8192;
constexpr int JP = 49;           // padded stride for score LDS
constexpr int TB = 8;            // tokens per PV-block

typedef short bf16x8 __attribute__((ext_vector_type(8)));
typedef float f32x4  __attribute__((ext_vector_type(4)));
typedef unsigned int u32x4 __attribute__((ext_vector_type(4)));

// 8 fp32 -> hi/lo bf16 fragments via v_cvt_pk_bf16_f32 (RNE).
__device__ inline void cvt8(float4 x0, float4 x1, bf16x8& hi, bf16x8& lo) {
    float xs[8] = {x0.x, x0.y, x0.z, x0.w, x1.x, x1.y, x1.z, x1.w};
    u32x4 hv, lv;
    #pragma unroll
    for (int p = 0; p < 4; ++p) {
        float a = xs[2 * p], b = xs[2 * p + 1];
        unsigned hp;
        asm("v_cvt_pk_bf16_f32 %0, %1, %2" : "=v"(hp) : "v"(a), "v"(b));
        float ha = __builtin_bit_cast(float, hp << 16);
        float hb = __builtin_bit_cast(float, hp & 0xffff0000u);
        float la = a - ha, lb = b - hb;
        unsigned lp;
        asm("v_cvt_pk_bf16_f32 %0, %1, %2" : "=v"(lp) : "v"(la), "v"(lb));
        hv[p] = hp; lv[p] = lp;
    }
    hi = __builtin_bit_cast(bf16x8, hv);
    lo = __builtin_bit_cast(bf16x8, lv);
}

// ---------------------------------------------------------------------------
// Kernel A: banded scores + softmax -> wm[NTOK][32] (fp32, workspace).
// 256 threads = 4 waves; wave w owns a 256-wide D-slice; LDS partial reduce.
// ---------------------------------------------------------------------------
__global__ __launch_bounds__(256, 2)
void scores_kernel(const float* __restrict__ h, float* __restrict__ wmg) {
    __shared__ float sc[4 * G * JP];   // per-wave partial scores [w][m][j]

    int bid = blockIdx.x, nblk = gridDim.x, lb = bid;
    if ((nblk & 7) == 0) {
        int per = nblk >> 3;
        lb = (bid & 7) * per + (bid >> 3);
    }

    const int tid  = threadIdx.x;
    const int w    = tid >> 6;
    const int lane = tid & 63;
    const int t0   = lb * G;
    const int s0   = t0 & (S_CONST - 1);
    const int jlim = (S_CONST - 2) - s0;

    // ---------------- scores via MFMA ---------------------------------------
    {
        const int d0   = w * 256;
        const int mrow = lane & 15;
        const int q8   = (lane >> 4) * 8;

        const float* A = h + (size_t)(t0 + mrow) * D + d0 + q8;
        int r0 = min(t0 +  1 + mrow, NTOK - 1);
        int r1 = min(t0 + 17 + mrow, NTOK - 1);
        int r2 = min(t0 + 33 + mrow, NTOK - 1);
        const float* B0 = h + (size_t)r0 * D + d0 + q8;
        const float* B1 = h + (size_t)r1 * D + d0 + q8;
        const float* B2 = h + (size_t)r2 * D + d0 + q8;

        f32x4 acc[3] = {{0,0,0,0},{0,0,0,0},{0,0,0,0}};

        float4 xa0 = *(const float4*)(A),  xa1 = *(const float4*)(A + 4);
        float4 x00 = *(const float4*)(B0), x01 = *(const float4*)(B0 + 4);
        float4 x10 = *(const float4*)(B1), x11 = *(const float4*)(B1 + 4);
        float4 x20 = *(const float4*)(B2), x21 = *(const float4*)(B2 + 4);

        #pragma unroll
        for (int kk = 0; kk < 8; ++kk) {
            float4 na0, na1, n00, n01, n10, n11, n20, n21;
            if (kk < 7) {
                const int o = (kk + 1) * 32;
                na0 = *(const float4*)(A  + o); na1 = *(const float4*)(A  + o + 4);
                n00 = *(const float4*)(B0 + o); n01 = *(const float4*)(B0 + o + 4);
                n10 = *(const float4*)(B1 + o); n11 = *(const float4*)(B1 + o + 4);
                n20 = *(const float4*)(B2 + o); n21 = *(const float4*)(B2 + o + 4);
            }

            bf16x8 ah, al, bh, bl;
            cvt8(xa0, xa1, ah, al);

            cvt8(x00, x01, bh, bl);
            acc[0] = __builtin_amdgcn_mfma_f32_16x16x32_bf16(ah, bh, acc[0], 0, 0, 0);
            acc[0] = __builtin_amdgcn_mfma_f32_16x16x32_bf16(ah, bl, acc[0], 0, 0, 0);
            acc[0] = __builtin_amdgcn_mfma_f32_16x16x32_bf16(al, bh, acc[0], 0, 0, 0);

            cvt8(x10, x11, bh, bl);
            acc[1] = __builtin_amdgcn_mfma_f32_16x16x32_bf16(ah, bh, acc[1], 0, 0, 0);
            acc[1] = __builtin_amdgcn_mfma_f32_16x16x32_bf16(ah, bl, acc[1], 0, 0, 0);
            acc[1] = __builtin_amdgcn_mfma_f32_16x16x32_bf16(al, bh, acc[1], 0, 0, 0);

            cvt8(x20, x21, bh, bl);
            acc[2] = __builtin_amdgcn_mfma_f32_16x16x32_bf16(ah, bh, acc[2], 0, 0, 0);
            acc[2] = __builtin_amdgcn_mfma_f32_16x16x32_bf16(ah, bl, acc[2], 0, 0, 0);
            acc[2] = __builtin_amdgcn_mfma_f32_16x16x32_bf16(al, bh, acc[2], 0, 0, 0);

            if (kk < 7) {
                xa0 = na0; xa1 = na1;
                x00 = n00; x01 = n01;
                x10 = n10; x11 = n11;
                x20 = n20; x21 = n21;
            }
        }

        // C layout: col = lane&15 (j within tile), row = (lane>>4)*4 + reg (token)
        #pragma unroll
        for (int t = 0; t < 3; ++t) {
            #pragma unroll
            for (int r = 0; r < 4; ++r) {
                int m = (lane >> 4) * 4 + r;
                int j = t * 16 + (lane & 15);
                sc[(w * G + m) * JP + j] = acc[t][r];
            }
        }
    }
    __syncthreads();

    // ---------------- reduce 4 partials + softmax -> global wm --------------
    {
        const int i   = tid >> 4;      // token 0..15
        const int sub = tid & 15;      // 16 threads per token

        float v[3];
        #pragma unroll
        for (int c = 0; c < 3; ++c) {
            int j = sub + c * 16;
            float s = sc[(0 * G + i) * JP + j] + sc[(1 * G + i) * JP + j]
                    + sc[(2 * G + i) * JP + j] + sc[(3 * G + i) * JP + j];
            bool valid = (j >= i) && (j <= i + 31) && (j <= jlim);
            v[c] = valid ? s : -1e9f;
        }
        float mx = fmaxf(v[0], fmaxf(v[1], v[2]));
        #pragma unroll
        for (int d = 1; d < 16; d <<= 1) mx = fmaxf(mx, __shfl_xor(mx, d, 16));

        float e[3];
        float sum = 0.f;
        #pragma unroll
        for (int c = 0; c < 3; ++c) { e[c] = __expf(v[c] - mx); sum += e[c]; }
        #pragma unroll
        for (int d = 1; d < 16; d <<= 1) sum += __shfl_xor(sum, d, 16);

        const bool any = (mx > -5e8f);
        const float inv = any ? (1.0f / sum) : 0.f;

        float* wrow = wmg + (size_t)(t0 + i) * 32;
        #pragma unroll
        for (int c = 0; c < 3; ++c) {
            int j = sub + c * 16;
            int k = j - i;                           // future offset 0..31
            if (k >= 0 && k < 32)
                wrow[k] = (j <= jlim) ? e[c] * inv : 0.f;
        }
    }
}

// ---------------------------------------------------------------------------
// Kernel B: PV streaming. Block = 8 tokens, 256 threads (thread = 16B D-chunk
// for all 8 tokens). 39-row sliding window, fully unrolled (static indexing).
// ---------------------------------------------------------------------------
__global__ __launch_bounds__(256, 4)
void pv_kernel(const float* __restrict__ h, const float* __restrict__ wm,
               float* __restrict__ out) {
    __shared__ float lw[TB * 32];      // 8 tokens x 32 weights

    int bid = blockIdx.x, nblk = gridDim.x, lb = bid;
    if ((nblk & 7) == 0) {
        int per = nblk >> 3;
        lb = (bid & 7) * per + (bid >> 3);
    }
    const int i0   = lb * TB;
    const int tid  = threadIdx.x;
    const int doff = tid * 4;

    lw[tid] = wm[(size_t)i0 * 32 + tid];           // 256 floats, coalesced
    __syncthreads();

    float4 acc[TB] = {};
    float4 wv[TB];                                  // rolling weight quads

    #pragma unroll
    for (int rr = 0; rr < TB + 31; ++rr) {          // rows i0+1 .. i0+39
        int r = min(i0 + 1 + rr, NTOK - 1);
        float4 f = *(const float4*)(h + (size_t)r * D + doff);
        #pragma unroll
        for (int t = 0; t < TB; ++t) {
            const int k = rr - t;                   // compile-time constant
            if (k >= 0 && k < 32) {
                if ((k & 3) == 0)
                    wv[t] = *(const float4*)(&lw[t * 32 + k]);
                const float wt = ((k & 3) == 0) ? wv[t].x :
                                 ((k & 3) == 1) ? wv[t].y :
                                 ((k & 3) == 2) ? wv[t].z : wv[t].w;
                acc[t].x += wt * f.x;
                acc[t].y += wt * f.y;
                acc[t].z += wt * f.z;
                acc[t].w += wt * f.w;
            }
        }
    }

    #pragma unroll
    for (int t = 0; t < TB; ++t)
        *(float4*)(out + (size_t)(i0 + t) * D + doff) = acc[t];
}

extern "C" void kernel_launch(void* const* d_in, const int* in_sizes, int n_in,
                              void* d_out, int out_size, void* d_ws, size_t ws_size,
                              hipStream_t stream) {
    const float* h = (const float*)d_in[0];
    float* out = (float*)d_out;
    float* wm = (float*)d_ws;                      // 8192*32*4 = 1 MiB
    const int ntok = in_sizes[0] / D;              // 8192

    scores_kernel<<<ntok / G, 256, 0, stream>>>(h, wm);
    pv_kernel<<<ntok / TB, 256, 0, stream>>>(h, wm, out);
}